// Round 3
// baseline (276.522 us; speedup 1.0000x reference)
//
#include <hip/hip_runtime.h>
#include <math.h>

// ---- problem constants ----
#define BATCH 512
#define CHAN 3
#define IMG 112
#define HW (IMG*IMG)            // 12544
#define K_TOT (CHAN*HW)         // 37632
#define NH 20
#define F4_TOT (K_TOT/4)        // 9408
#define KT 32                   // k-tiles
#define F4_PER_TILE (F4_TOT/KT) // 294
#define MBB 16                  // batches per block
#define NPW 5                   // n-outputs per wave (4 waves * 5 = 20)

// Kernel 0: W1 [37632][20] -> W1T [20][37632]. 147 blocks x 256.
__global__ __launch_bounds__(256)
void transpose_w1(const float* __restrict__ W1, float* __restrict__ W1T) {
    const int k = blockIdx.x * 256 + threadIdx.x;   // < 37632 (147*256 exact)
    float4 r[5];
    #pragma unroll
    for (int q = 0; q < 5; ++q)
        r[q] = *reinterpret_cast<const float4*>(W1 + (long)k * NH + q * 4);
    const float* f = reinterpret_cast<const float*>(r);
    #pragma unroll
    for (int n = 0; n < NH; ++n)
        W1T[(long)n * K_TOT + k] = f[n];            // coalesced stores per n
}

// Kernel 1: partial h = img @ W1 over a K-chunk.
// grid (KT, 512/MBB=32), block 256 (4 waves). Wave w computes n in [5w,5w+5)
// for 16 batches. Lane owns a float4 of k -> ALL loads coalesced.
__global__ __launch_bounds__(256)
void gemm1_kernel(const float* __restrict__ img, const float* __restrict__ W1T,
                  float* __restrict__ partial) {
    const int tid  = threadIdx.x;
    const int wave = tid >> 6, lane = tid & 63;
    const int kt   = blockIdx.x;
    const int b0   = blockIdx.y * MBB;
    const int n0   = wave * NPW;

    float acc[MBB][NPW];
    #pragma unroll
    for (int b = 0; b < MBB; ++b)
        #pragma unroll
        for (int n = 0; n < NPW; ++n) acc[b][n] = 0.f;

    const int f4start = kt * F4_PER_TILE;
    const int f4end   = f4start + F4_PER_TILE;

    for (int f = f4start + lane; f < f4end; f += 64) {
        const int k = f * 4;
        float4 wq[NPW];
        #pragma unroll
        for (int n = 0; n < NPW; ++n)
            wq[n] = *reinterpret_cast<const float4*>(W1T + (long)(n0 + n) * K_TOT + k);
        #pragma unroll
        for (int b = 0; b < MBB; ++b) {
            const float4 iv = *reinterpret_cast<const float4*>(img + (long)(b0 + b) * K_TOT + k);
            #pragma unroll
            for (int n = 0; n < NPW; ++n) {
                acc[b][n] = fmaf(iv.x, wq[n].x, acc[b][n]);
                acc[b][n] = fmaf(iv.y, wq[n].y, acc[b][n]);
                acc[b][n] = fmaf(iv.z, wq[n].z, acc[b][n]);
                acc[b][n] = fmaf(iv.w, wq[n].w, acc[b][n]);
            }
        }
    }

    // full-wave butterfly reduction; lane 0 writes partials
    #pragma unroll
    for (int b = 0; b < MBB; ++b)
        #pragma unroll
        for (int n = 0; n < NPW; ++n) {
            float v = acc[b][n];
            #pragma unroll
            for (int off = 32; off > 0; off >>= 1) v += __shfl_xor(v, off, 64);
            acc[b][n] = v;
        }
    if (lane == 0) {
        #pragma unroll
        for (int b = 0; b < MBB; ++b)
            #pragma unroll
            for (int n = 0; n < NPW; ++n)
                partial[((long)kt * BATCH + (b0 + b)) * NH + (n0 + n)] = acc[b][n];
    }
}

// Kernel 2: one 64-thread block per batch.
__global__ __launch_bounds__(64)
void theta_kernel(const float* __restrict__ partial, const float* __restrict__ b1,
                  const float* __restrict__ W2, const float* __restrict__ b2,
                  float* __restrict__ theta) {
    const int b = blockIdx.x;
    const int t = threadIdx.x;
    __shared__ float h[NH];
    if (t < NH) {
        float s = b1[t];
        #pragma unroll
        for (int kt = 0; kt < KT; ++kt)
            s += partial[((long)kt * BATCH + b) * NH + t];
        h[t] = tanhf(s);
    }
    __syncthreads();
    if (t < 6) {
        float s = b2[t];
        #pragma unroll
        for (int n = 0; n < NH; ++n) s = fmaf(h[n], W2[n * 6 + t], s);
        theta[b * 6 + t] = tanhf(s);
    }
}

// Kernel 3: affine_grid + grid_sample (bilinear, zeros, align_corners=False)
// 4 consecutive x-pixels per thread -> float4 stores, all 3 channels.
#define QUADS (HW/4)            // 3136
__global__ __launch_bounds__(256)
void warp_kernel(const float* __restrict__ img, const float* __restrict__ theta,
                 float* __restrict__ out) {
    const int b = blockIdx.y;
    const int quad = blockIdx.x * 256 + threadIdx.x;
    if (quad >= QUADS) return;
    const int y  = quad / (IMG / 4);          // 28 quads per row
    const int x0 = (quad - y * (IMG / 4)) * 4;

    const float* t = theta + b * 6;
    const float t0 = t[0], t1 = t[1], t2 = t[2], t3 = t[3], t4 = t[4], t5 = t[5];
    const float ys = (2.f * y + 1.f) / (float)IMG - 1.f;

    const long ib = (long)b * CHAN * HW;
    float res[CHAN][4];

    #pragma unroll
    for (int i = 0; i < 4; ++i) {
        const float xs = (2.f * (x0 + i) + 1.f) / (float)IMG - 1.f;
        const float gx = t0 * xs + t1 * ys + t2;
        const float gy = t3 * xs + t4 * ys + t5;

        const float ix = ((gx + 1.f) * (float)IMG - 1.f) * 0.5f;
        const float iy = ((gy + 1.f) * (float)IMG - 1.f) * 0.5f;

        const float x0f = floorf(ix), y0f = floorf(iy);
        const float wx1 = ix - x0f, wx0 = 1.f - wx1;
        const float wy1 = iy - y0f, wy0 = 1.f - wy1;
        const int sx0 = (int)x0f, sy0 = (int)y0f;
        const int sx1 = sx0 + 1, sy1 = sy0 + 1;

        const bool vx0 = (sx0 >= 0) & (sx0 <= IMG - 1);
        const bool vx1 = (sx1 >= 0) & (sx1 <= IMG - 1);
        const bool vy0 = (sy0 >= 0) & (sy0 <= IMG - 1);
        const bool vy1 = (sy1 >= 0) & (sy1 <= IMG - 1);
        const int cx0 = min(max(sx0, 0), IMG - 1), cx1 = min(max(sx1, 0), IMG - 1);
        const int cy0 = min(max(sy0, 0), IMG - 1), cy1 = min(max(sy1, 0), IMG - 1);

        const float w00 = (vx0 && vy0) ? wx0 * wy0 : 0.f;
        const float w10 = (vx1 && vy0) ? wx1 * wy0 : 0.f;
        const float w01 = (vx0 && vy1) ? wx0 * wy1 : 0.f;
        const float w11 = (vx1 && vy1) ? wx1 * wy1 : 0.f;

        const int o00 = cy0 * IMG + cx0, o10 = cy0 * IMG + cx1;
        const int o01 = cy1 * IMG + cx0, o11 = cy1 * IMG + cx1;
        #pragma unroll
        for (int c = 0; c < CHAN; ++c) {
            const float* p = img + ib + (long)c * HW;
            res[c][i] = w00 * p[o00] + w10 * p[o10] + w01 * p[o01] + w11 * p[o11];
        }
    }

    const int pix0 = y * IMG + x0;
    #pragma unroll
    for (int c = 0; c < CHAN; ++c) {
        float4 v = make_float4(res[c][0], res[c][1], res[c][2], res[c][3]);
        *reinterpret_cast<float4*>(out + ib + (long)c * HW + pix0) = v;
    }
}

extern "C" void kernel_launch(void* const* d_in, const int* in_sizes, int n_in,
                              void* d_out, int out_size, void* d_ws, size_t ws_size,
                              hipStream_t stream) {
    const float* img = (const float*)d_in[0];
    const float* W1  = (const float*)d_in[1];
    const float* b1  = (const float*)d_in[2];
    const float* W2  = (const float*)d_in[3];
    const float* b2  = (const float*)d_in[4];
    float* out = (float*)d_out;

    float* partial = (float*)d_ws;                     // [KT][512][20]  (1.31 MB)
    float* theta   = partial + (long)KT * BATCH * NH;  // [512][6]
    float* W1T     = theta + BATCH * 6;                // [20][37632]    (3 MB)

    transpose_w1<<<dim3(K_TOT / 256), 256, 0, stream>>>(W1, W1T);
    gemm1_kernel<<<dim3(KT, BATCH / MBB), 256, 0, stream>>>(img, W1T, partial);
    theta_kernel<<<dim3(BATCH), 64, 0, stream>>>(partial, b1, W2, b2, theta);
    warp_kernel<<<dim3((QUADS + 255) / 256, BATCH), 256, 0, stream>>>(img, theta, out);
}

// Round 5
// 225.360 us; speedup vs baseline: 1.2270x; 1.2270x over previous
//
#include <hip/hip_runtime.h>
#include <math.h>

// ---- problem constants ----
#define BATCH 512
#define CHAN 3
#define IMG 112
#define HW (IMG*IMG)            // 12544
#define K_TOT (CHAN*HW)         // 37632
#define NH 20
#define F4_TOT (K_TOT/4)        // 9408
#define KT 21                   // k-tiles: F4_PER_TILE = 448 = 7*64 exact
#define F4_PER_TILE (F4_TOT/KT) // 448
#define MBB 8                   // batches per block
#define NPW 5                   // n per wave (4 waves * 5 = 20)

// Kernel 0: W1 [37632][20] -> W1T [20][37632]. 147 blocks x 256.
__global__ __launch_bounds__(256)
void transpose_w1(const float* __restrict__ W1, float* __restrict__ W1T) {
    const int k = blockIdx.x * 256 + threadIdx.x;   // < 37632 (147*256 exact)
    float4 r[5];
    #pragma unroll
    for (int q = 0; q < 5; ++q)
        r[q] = *reinterpret_cast<const float4*>(W1 + (long)k * NH + q * 4);
    const float* f = reinterpret_cast<const float*>(r);
    #pragma unroll
    for (int n = 0; n < NH; ++n)
        W1T[(long)n * K_TOT + k] = f[n];            // coalesced stores per n
}

// Kernel 1: partial h = img @ W1 over a K-chunk.
// grid (KT, 512/MBB=64), block 256 (4 waves). Wave w owns n in [5w, 5w+5),
// 8 batches. acc = 40 VGPR; 13 independent float4 loads in flight per iter.
__global__ __launch_bounds__(256)
void gemm1_kernel(const float* __restrict__ img, const float* __restrict__ W1T,
                  float* __restrict__ partial) {
    const int tid  = threadIdx.x;
    const int wave = tid >> 6, lane = tid & 63;
    const int kt   = blockIdx.x;
    const int b0   = blockIdx.y * MBB;
    const int n0   = wave * NPW;

    float acc[MBB][NPW];
    #pragma unroll
    for (int b = 0; b < MBB; ++b)
        #pragma unroll
        for (int n = 0; n < NPW; ++n) acc[b][n] = 0.f;

    const int f4start = kt * F4_PER_TILE;

    #pragma unroll 1
    for (int it = 0; it < F4_PER_TILE / 64; ++it) {
        const int k = (f4start + it * 64 + lane) * 4;
        float4 wq[NPW];
        float4 iv[MBB];
        #pragma unroll
        for (int n = 0; n < NPW; ++n)
            wq[n] = *reinterpret_cast<const float4*>(W1T + (long)(n0 + n) * K_TOT + k);
        #pragma unroll
        for (int b = 0; b < MBB; ++b)
            iv[b] = *reinterpret_cast<const float4*>(img + (long)(b0 + b) * K_TOT + k);

        #pragma unroll
        for (int b = 0; b < MBB; ++b)
            #pragma unroll
            for (int n = 0; n < NPW; ++n) {
                acc[b][n] = fmaf(iv[b].x, wq[n].x, acc[b][n]);
                acc[b][n] = fmaf(iv[b].y, wq[n].y, acc[b][n]);
                acc[b][n] = fmaf(iv[b].z, wq[n].z, acc[b][n]);
                acc[b][n] = fmaf(iv[b].w, wq[n].w, acc[b][n]);
            }
    }

    // butterfly reduce each of the 40 values across the wave; lane 0 -> LDS
    __shared__ float red[MBB * NH];       // [b_local][n] = 160 floats
    #pragma unroll
    for (int b = 0; b < MBB; ++b)
        #pragma unroll
        for (int n = 0; n < NPW; ++n) {
            float v = acc[b][n];
            #pragma unroll
            for (int off = 32; off > 0; off >>= 1) v += __shfl_xor(v, off, 64);
            if (lane == 0) red[b * NH + (n0 + n)] = v;
        }
    __syncthreads();
    // coalesced write: 160 contiguous floats
    if (tid < MBB * NH)
        partial[((long)kt * BATCH + b0) * NH + tid] = red[tid];
}

// Kernel 2: one 64-thread block per batch.
__global__ __launch_bounds__(64)
void theta_kernel(const float* __restrict__ partial, const float* __restrict__ b1,
                  const float* __restrict__ W2, const float* __restrict__ b2,
                  float* __restrict__ theta) {
    const int b = blockIdx.x;
    const int t = threadIdx.x;
    __shared__ float h[NH];
    if (t < NH) {
        float s = b1[t];
        #pragma unroll
        for (int kt = 0; kt < KT; ++kt)
            s += partial[((long)kt * BATCH + b) * NH + t];
        h[t] = tanhf(s);
    }
    __syncthreads();
    if (t < 6) {
        float s = b2[t];
        #pragma unroll
        for (int n = 0; n < NH; ++n) s = fmaf(h[n], W2[n * 6 + t], s);
        theta[b * 6 + t] = tanhf(s);
    }
}

// Kernel 3: affine_grid + grid_sample (bilinear, zeros, align_corners=False)
// 4 consecutive x-pixels per thread -> float4 stores, all 3 channels.
#define QUADS (HW/4)            // 3136
__global__ __launch_bounds__(256)
void warp_kernel(const float* __restrict__ img, const float* __restrict__ theta,
                 float* __restrict__ out) {
    const int b = blockIdx.y;
    const int quad = blockIdx.x * 256 + threadIdx.x;
    if (quad >= QUADS) return;
    const int y  = quad / (IMG / 4);          // 28 quads per row
    const int x0 = (quad - y * (IMG / 4)) * 4;

    const float* t = theta + b * 6;
    const float t0 = t[0], t1 = t[1], t2 = t[2], t3 = t[3], t4 = t[4], t5 = t[5];
    const float ys = (2.f * y + 1.f) / (float)IMG - 1.f;

    const long ib = (long)b * CHAN * HW;
    float res[CHAN][4];

    #pragma unroll
    for (int i = 0; i < 4; ++i) {
        const float xs = (2.f * (x0 + i) + 1.f) / (float)IMG - 1.f;
        const float gx = t0 * xs + t1 * ys + t2;
        const float gy = t3 * xs + t4 * ys + t5;

        const float ix = ((gx + 1.f) * (float)IMG - 1.f) * 0.5f;
        const float iy = ((gy + 1.f) * (float)IMG - 1.f) * 0.5f;

        const float x0f = floorf(ix), y0f = floorf(iy);
        const float wx1 = ix - x0f, wx0 = 1.f - wx1;
        const float wy1 = iy - y0f, wy0 = 1.f - wy1;
        const int sx0 = (int)x0f, sy0 = (int)y0f;
        const int sx1 = sx0 + 1, sy1 = sy0 + 1;

        const bool vx0 = (sx0 >= 0) & (sx0 <= IMG - 1);
        const bool vx1 = (sx1 >= 0) & (sx1 <= IMG - 1);
        const bool vy0 = (sy0 >= 0) & (sy0 <= IMG - 1);
        const bool vy1 = (sy1 >= 0) & (sy1 <= IMG - 1);
        const int cx0 = min(max(sx0, 0), IMG - 1), cx1 = min(max(sx1, 0), IMG - 1);
        const int cy0 = min(max(sy0, 0), IMG - 1), cy1 = min(max(sy1, 0), IMG - 1);

        const float w00 = (vx0 && vy0) ? wx0 * wy0 : 0.f;
        const float w10 = (vx1 && vy0) ? wx1 * wy0 : 0.f;
        const float w01 = (vx0 && vy1) ? wx0 * wy1 : 0.f;
        const float w11 = (vx1 && vy1) ? wx1 * wy1 : 0.f;

        const int o00 = cy0 * IMG + cx0, o10 = cy0 * IMG + cx1;
        const int o01 = cy1 * IMG + cx0, o11 = cy1 * IMG + cx1;
        #pragma unroll
        for (int c = 0; c < CHAN; ++c) {
            const float* p = img + ib + (long)c * HW;
            res[c][i] = w00 * p[o00] + w10 * p[o10] + w01 * p[o01] + w11 * p[o11];
        }
    }

    const int pix0 = y * IMG + x0;
    #pragma unroll
    for (int c = 0; c < CHAN; ++c) {
        float4 v = make_float4(res[c][0], res[c][1], res[c][2], res[c][3]);
        *reinterpret_cast<float4*>(out + ib + (long)c * HW + pix0) = v;
    }
}

extern "C" void kernel_launch(void* const* d_in, const int* in_sizes, int n_in,
                              void* d_out, int out_size, void* d_ws, size_t ws_size,
                              hipStream_t stream) {
    const float* img = (const float*)d_in[0];
    const float* W1  = (const float*)d_in[1];
    const float* b1  = (const float*)d_in[2];
    const float* W2  = (const float*)d_in[3];
    const float* b2  = (const float*)d_in[4];
    float* out = (float*)d_out;

    float* partial = (float*)d_ws;                     // [KT][512][20]  (~840 KB)
    float* theta   = partial + (long)KT * BATCH * NH;  // [512][6]
    float* W1T     = theta + BATCH * 6;                // [20][37632]    (3 MB)

    transpose_w1<<<dim3(K_TOT / 256), 256, 0, stream>>>(W1, W1T);
    gemm1_kernel<<<dim3(KT, BATCH / MBB), 256, 0, stream>>>(img, W1T, partial);
    theta_kernel<<<dim3(BATCH), 64, 0, stream>>>(partial, b1, W2, b2, theta);
    warp_kernel<<<dim3((QUADS + 255) / 256, BATCH), 256, 0, stream>>>(img, theta, out);
}

// Round 6
// 202.188 us; speedup vs baseline: 1.3676x; 1.1146x over previous
//
#include <hip/hip_runtime.h>
#include <math.h>

// ---- problem constants ----
#define BATCH 512
#define CHAN 3
#define IMG 112
#define HW (IMG*IMG)            // 12544
#define K_TOT (CHAN*HW)         // 37632
#define NH 20
#define F4_TOT (K_TOT/4)        // 9408
#define KT 21                   // k-tiles: F4_PER_TILE = 448 = 7*64 exact
#define F4_PER_TILE (F4_TOT/KT) // 448
#define ITERS (F4_PER_TILE/64)  // 7
#define MBB 8                   // batches per block
#define NPW 5                   // n per wave (4 waves * 5 = 20)

// Kernel 0: W1 [37632][20] -> W1T [20][37632]. 147 blocks x 256.
__global__ __launch_bounds__(256)
void transpose_w1(const float* __restrict__ W1, float* __restrict__ W1T) {
    const int k = blockIdx.x * 256 + threadIdx.x;   // < 37632 (147*256 exact)
    float4 r[5];
    #pragma unroll
    for (int q = 0; q < 5; ++q)
        r[q] = *reinterpret_cast<const float4*>(W1 + (long)k * NH + q * 4);
    const float* f = reinterpret_cast<const float*>(r);
    #pragma unroll
    for (int n = 0; n < NH; ++n)
        W1T[(long)n * K_TOT + k] = f[n];            // coalesced stores per n
}

// Kernel 1: partial h = img @ W1 over a K-chunk.
// grid (KT, 512/MBB=64), block 256 (4 waves). Wave w owns n in [5w,5w+5),
// 8 batches. 2-deep software pipeline: load iter t+1 while FMA-ing iter t.
__global__ __launch_bounds__(256)
void gemm1_kernel(const float* __restrict__ img, const float* __restrict__ W1T,
                  float* __restrict__ partial) {
    const int tid  = threadIdx.x;
    const int wave = tid >> 6, lane = tid & 63;
    const int kt   = blockIdx.x;
    const int b0   = blockIdx.y * MBB;
    const int n0   = wave * NPW;
    const int f4start = kt * F4_PER_TILE;

    float acc[MBB][NPW];
    #pragma unroll
    for (int b = 0; b < MBB; ++b)
        #pragma unroll
        for (int n = 0; n < NPW; ++n) acc[b][n] = 0.f;

    float4 wqA[NPW], ivA[MBB], wqB[NPW], ivB[MBB];

#define LOADS(WQ, IV, IT)                                                        \
    {                                                                            \
        const int k_ = (f4start + (IT) * 64 + lane) * 4;                         \
        _Pragma("unroll")                                                        \
        for (int n = 0; n < NPW; ++n)                                            \
            WQ[n] = *reinterpret_cast<const float4*>(W1T + (long)(n0 + n) * K_TOT + k_); \
        _Pragma("unroll")                                                        \
        for (int b = 0; b < MBB; ++b)                                            \
            IV[b] = *reinterpret_cast<const float4*>(img + (long)(b0 + b) * K_TOT + k_); \
    }

#define FMAS(WQ, IV)                                                             \
    {                                                                            \
        _Pragma("unroll")                                                        \
        for (int b = 0; b < MBB; ++b)                                            \
            _Pragma("unroll")                                                    \
            for (int n = 0; n < NPW; ++n) {                                      \
                acc[b][n] = fmaf(IV[b].x, WQ[n].x, acc[b][n]);                   \
                acc[b][n] = fmaf(IV[b].y, WQ[n].y, acc[b][n]);                   \
                acc[b][n] = fmaf(IV[b].z, WQ[n].z, acc[b][n]);                   \
                acc[b][n] = fmaf(IV[b].w, WQ[n].w, acc[b][n]);                   \
            }                                                                    \
    }

    LOADS(wqA, ivA, 0);
    #pragma unroll 1
    for (int it = 0; it < ITERS - 1; it += 2) {
        LOADS(wqB, ivB, it + 1);
        FMAS(wqA, ivA);
        LOADS(wqA, ivA, it + 2);
        FMAS(wqB, ivB);
    }
    FMAS(wqA, ivA);     // iteration 6

    // butterfly reduce each of the 40 values across the wave; lane 0 -> LDS
    __shared__ float red[MBB * NH];       // [b_local][n] = 160 floats
    #pragma unroll
    for (int b = 0; b < MBB; ++b)
        #pragma unroll
        for (int n = 0; n < NPW; ++n) {
            float v = acc[b][n];
            #pragma unroll
            for (int off = 32; off > 0; off >>= 1) v += __shfl_xor(v, off, 64);
            if (lane == 0) red[b * NH + (n0 + n)] = v;
        }
    __syncthreads();
    // coalesced write: 160 contiguous floats
    if (tid < MBB * NH)
        partial[((long)kt * BATCH + b0) * NH + tid] = red[tid];
}

// Kernel 2: one 64-thread block per batch.
__global__ __launch_bounds__(64)
void theta_kernel(const float* __restrict__ partial, const float* __restrict__ b1,
                  const float* __restrict__ W2, const float* __restrict__ b2,
                  float* __restrict__ theta) {
    const int b = blockIdx.x;
    const int t = threadIdx.x;
    __shared__ float h[NH];
    if (t < NH) {
        float s = b1[t];
        #pragma unroll
        for (int kt = 0; kt < KT; ++kt)
            s += partial[((long)kt * BATCH + b) * NH + t];
        h[t] = tanhf(s);
    }
    __syncthreads();
    if (t < 6) {
        float s = b2[t];
        #pragma unroll
        for (int n = 0; n < NH; ++n) s = fmaf(h[n], W2[n * 6 + t], s);
        theta[b * 6 + t] = tanhf(s);
    }
}

// Kernel 3: grid_sample via LDS-staged source plane.
// grid (BATCH, CHAN), block 256. Stage img[b][c] (49 KB) in LDS, then each
// thread produces quads of 4 output pixels; all gathers hit LDS.
#define QUADS (HW/4)            // 3136
__global__ __launch_bounds__(256)
void warp_kernel(const float* __restrict__ img, const float* __restrict__ theta,
                 float* __restrict__ out) {
    const int b = blockIdx.x;
    const int c = blockIdx.y;
    const long ibc = ((long)b * CHAN + c) * HW;

    __shared__ float tile[HW];  // 50176 B -> 3 blocks/CU
    for (int i = threadIdx.x; i < HW / 4; i += 256)
        reinterpret_cast<float4*>(tile)[i] =
            reinterpret_cast<const float4*>(img + ibc)[i];

    const float* t = theta + b * 6;
    const float t0 = t[0], t1 = t[1], t2 = t[2], t3 = t[3], t4 = t[4], t5 = t[5];
    __syncthreads();

    #pragma unroll 1
    for (int q = threadIdx.x; q < QUADS; q += 256) {
        const int y  = q / (IMG / 4);            // 28 quads per row
        const int x0 = (q - y * (IMG / 4)) * 4;
        const float ys = (2.f * y + 1.f) / (float)IMG - 1.f;
        float res[4];

        #pragma unroll
        for (int i = 0; i < 4; ++i) {
            const float xs = (2.f * (x0 + i) + 1.f) / (float)IMG - 1.f;
            const float gx = t0 * xs + t1 * ys + t2;
            const float gy = t3 * xs + t4 * ys + t5;

            const float ix = ((gx + 1.f) * (float)IMG - 1.f) * 0.5f;
            const float iy = ((gy + 1.f) * (float)IMG - 1.f) * 0.5f;

            const float x0f = floorf(ix), y0f = floorf(iy);
            const float wx1 = ix - x0f, wx0 = 1.f - wx1;
            const float wy1 = iy - y0f, wy0 = 1.f - wy1;
            const int sx0 = (int)x0f, sy0 = (int)y0f;
            const int sx1 = sx0 + 1, sy1 = sy0 + 1;

            const bool vx0 = (sx0 >= 0) & (sx0 <= IMG - 1);
            const bool vx1 = (sx1 >= 0) & (sx1 <= IMG - 1);
            const bool vy0 = (sy0 >= 0) & (sy0 <= IMG - 1);
            const bool vy1 = (sy1 >= 0) & (sy1 <= IMG - 1);
            const int cx0 = min(max(sx0, 0), IMG - 1), cx1 = min(max(sx1, 0), IMG - 1);
            const int cy0 = min(max(sy0, 0), IMG - 1), cy1 = min(max(sy1, 0), IMG - 1);

            const float w00 = (vx0 && vy0) ? wx0 * wy0 : 0.f;
            const float w10 = (vx1 && vy0) ? wx1 * wy0 : 0.f;
            const float w01 = (vx0 && vy1) ? wx0 * wy1 : 0.f;
            const float w11 = (vx1 && vy1) ? wx1 * wy1 : 0.f;

            const float v00 = tile[cy0 * IMG + cx0];
            const float v10 = tile[cy0 * IMG + cx1];
            const float v01 = tile[cy1 * IMG + cx0];
            const float v11 = tile[cy1 * IMG + cx1];
            res[i] = w00 * v00 + w10 * v10 + w01 * v01 + w11 * v11;
        }

        *reinterpret_cast<float4*>(out + ibc + y * IMG + x0) =
            make_float4(res[0], res[1], res[2], res[3]);
    }
}

extern "C" void kernel_launch(void* const* d_in, const int* in_sizes, int n_in,
                              void* d_out, int out_size, void* d_ws, size_t ws_size,
                              hipStream_t stream) {
    const float* img = (const float*)d_in[0];
    const float* W1  = (const float*)d_in[1];
    const float* b1  = (const float*)d_in[2];
    const float* W2  = (const float*)d_in[3];
    const float* b2  = (const float*)d_in[4];
    float* out = (float*)d_out;

    float* partial = (float*)d_ws;                     // [KT][512][20]  (~840 KB)
    float* theta   = partial + (long)KT * BATCH * NH;  // [512][6]
    float* W1T     = theta + BATCH * 6;                // [20][37632]    (3 MB)

    transpose_w1<<<dim3(K_TOT / 256), 256, 0, stream>>>(W1, W1T);
    gemm1_kernel<<<dim3(KT, BATCH / MBB), 256, 0, stream>>>(img, W1T, partial);
    theta_kernel<<<dim3(BATCH), 64, 0, stream>>>(partial, b1, W2, b2, theta);
    warp_kernel<<<dim3(BATCH, CHAN), 256, 0, stream>>>(img, theta, out);
}